// Round 1
// baseline (499.263 us; speedup 1.0000x reference)
//
#include <hip/hip_runtime.h>
#include <hip/hip_bf16.h>

// Problem constants (from the reference): B,T,V,E,U = 256,512,20000,128,128
#define BB 256
#define TT 512
#define VV 20000
#define EE 128
#define UU 128
#define G4 512   // 4*U gate width

// Fast device math: error ~1e-6, vastly under the 1e-2 absmax threshold.
__device__ __forceinline__ float sigmoid_f(float x) {
    float e = __expf(-x);                       // v_exp_f32 based
    return __builtin_amdgcn_rcpf(1.0f + e);     // v_rcp_f32 (saturates correctly at +/-inf)
}
__device__ __forceinline__ float tanh_f(float x) {
    // tanh(x) = 1 - 2/(exp(2x)+1); exp overflow -> rcp(inf)=0 -> +1, underflow -> -1
    float e = __expf(2.0f * x);
    return 1.0f - 2.0f * __builtin_amdgcn_rcpf(e + 1.0f);
}

// ---------------------------------------------------------------------------
// Phase 1: projected-token table  P[v][g] = sum_e emb[v][e]*K[e][g] + bias[g]
// Only 20000 distinct tokens vs 131072 (b,t) pairs -> 3.3x less GEMM work and
// 41 MB (L3-resident) instead of 256 MB of zx.
// Block: 512 threads = 512 gate columns; 16 emb rows per block (20000/16=1250).
// ---------------------------------------------------------------------------
__global__ __launch_bounds__(512, 2) void proj_kernel(
    const float* __restrict__ emb, const float* __restrict__ wk,
    const float* __restrict__ bias, float* __restrict__ P) {
    const int col = threadIdx.x;           // 0..511  (gate column)
    const int v0  = blockIdx.x * 16;       // first emb row of this block

    __shared__ float elds[16 * EE];        // 16 emb rows, 8 KB
    // 16 rows x 128 f32 = 2048 floats contiguous; 512 threads x float4
    ((float4*)elds)[col] = ((const float4*)(emb + (size_t)v0 * EE))[col];
    __syncthreads();

    float bcol = bias[col];
    float acc[16];
#pragma unroll
    for (int r = 0; r < 16; ++r) acc[r] = bcol;

    const float4* elds4 = (const float4*)elds;
    for (int e0 = 0; e0 < EE; e0 += 4) {
        // coalesced across col (stride-1); rows of K are 2KB apart
        float k0 = wk[(e0 + 0) * G4 + col];
        float k1 = wk[(e0 + 1) * G4 + col];
        float k2 = wk[(e0 + 2) * G4 + col];
        float k3 = wk[(e0 + 3) * G4 + col];
#pragma unroll
        for (int r = 0; r < 16; ++r) {
            float4 ev = elds4[r * 32 + (e0 >> 2)];   // LDS broadcast read (conflict-free)
            acc[r] = fmaf(ev.x, k0, acc[r]);
            acc[r] = fmaf(ev.y, k1, acc[r]);
            acc[r] = fmaf(ev.z, k2, acc[r]);
            acc[r] = fmaf(ev.w, k3, acc[r]);
        }
    }
#pragma unroll
    for (int r = 0; r < 16; ++r)
        P[(size_t)(v0 + r) * G4 + col] = acc[r];     // coalesced store
}

// ---------------------------------------------------------------------------
// Phase 2: the sequential LSTM. One block per batch row (256 blocks ~ 1/CU),
// 512 threads = 512 gate columns. Each thread holds its recurrent-kernel
// column in 128 VGPRs (zero per-step weight traffic). h (128 f32) is
// broadcast via LDS; gates exchanged via a 2KB LDS buffer; 2 barriers/step.
// P[token] gather for step t+1 is prefetched during step t.
// ---------------------------------------------------------------------------
__global__ __launch_bounds__(512, 2) void lstm_kernel(
    const int* __restrict__ tokens, const float* __restrict__ rk,
    const float* __restrict__ P, const float* __restrict__ dense_w,
    const float* __restrict__ dense_b, float* __restrict__ out) {
    const int col = threadIdx.x;           // gate column 0..511
    const int b   = blockIdx.x;            // batch row

    __shared__ float4 h4[UU / 4];          // h broadcast buffer (128 f32)
    __shared__ float  gbuf[G4];            // activated gates
    float* hf = (float*)h4;

    // Recurrent kernel column -> registers (~128 VGPR, fits 2 waves/SIMD)
    float rkreg[EE];
#pragma unroll
    for (int k = 0; k < EE; ++k) rkreg[k] = rk[k * G4 + col];

    if (col < UU) hf[col] = 0.0f;          // h0 = 0
    float c = 0.0f, hv = 0.0f;             // c0 = 0 (c,h owned by threads 0..127)

    const int* trow = tokens + (size_t)b * TT;
    float pf = P[(size_t)trow[0] * G4 + col];   // prologue gather for t=0
    __syncthreads();

    for (int t = 0; t < TT; ++t) {
        // --- prefetch next step's P value (hides L3/HBM gather latency) ---
        int tn   = (t + 1 < TT) ? (t + 1) : (TT - 1);
        int tokn = trow[tn];                          // wave-uniform -> s_load
        float pfn = P[(size_t)tokn * G4 + col];       // coalesced 2KB/block

        // --- z[col] = P + h @ rk[:,col]  (weights in registers) ---
        float acc = pf;
#pragma unroll
        for (int kk = 0; kk < UU / 4; ++kk) {
            float4 hvv = h4[kk];                      // ds_read_b128 broadcast
            acc = fmaf(hvv.x, rkreg[4 * kk + 0], acc);
            acc = fmaf(hvv.y, rkreg[4 * kk + 1], acc);
            acc = fmaf(hvv.z, rkreg[4 * kk + 2], acc);
            acc = fmaf(hvv.w, rkreg[4 * kk + 3], acc);
        }

        // --- activation (wave-uniform branches: gate bounds are multiples of 64) ---
        float a;
        if (col < 256)      a = sigmoid_f(acc);  // i, f
        else if (col < 384) a = tanh_f(acc);     // g
        else                a = sigmoid_f(acc);  // o
        gbuf[col] = a;
        __syncthreads();

        // --- state update (threads 0..127 = units) ---
        if (col < UU) {
            float gi = gbuf[col];
            float gf = gbuf[col + UU];
            float gg = gbuf[col + 2 * UU];
            float go = gbuf[col + 3 * UU];
            c  = fmaf(gf, c, gi * gg);
            hv = go * tanh_f(c);
            hf[col] = hv;                 // publish h for next step
        }
        pf = pfn;
        __syncthreads();
    }

    // --- dense sigmoid head: out[b] = sigmoid(h @ w + b) ---
    if (col < UU) gbuf[col] = hv * dense_w[col];
    __syncthreads();
    if (col == 0) {
        float s = dense_b[0];
        for (int u = 0; u < UU; ++u) s += gbuf[u];
        out[b] = sigmoid_f(s);
    }
}

extern "C" void kernel_launch(void* const* d_in, const int* in_sizes, int n_in,
                              void* d_out, int out_size, void* d_ws, size_t ws_size,
                              hipStream_t stream) {
    const int*   tokens = (const int*)  d_in[0];
    const float* emb    = (const float*)d_in[1];
    const float* wk     = (const float*)d_in[2];
    const float* rk     = (const float*)d_in[3];
    const float* bias   = (const float*)d_in[4];
    const float* dw     = (const float*)d_in[5];
    const float* db     = (const float*)d_in[6];
    float* out = (float*)d_out;
    float* P   = (float*)d_ws;     // needs 20000*512*4 = 40.96 MB of scratch

    proj_kernel<<<VV / 16, 512, 0, stream>>>(emb, wk, bias, P);
    lstm_kernel<<<BB, 512, 0, stream>>>(tokens, rk, P, dw, db, out);
}

// Round 2
// 381.306 us; speedup vs baseline: 1.3094x; 1.3094x over previous
//
#include <hip/hip_runtime.h>
#include <hip/hip_bf16.h>

// Problem constants: B,T,V,E,U = 256,512,20000,128,128
#define BB 256
#define TT 512
#define VV 20000
#define EE 128
#define UU 128
#define G4 512   // 4*U gate width

typedef _Float16 half2v __attribute__((ext_vector_type(2)));

// Fast device math: error ~1e-6, vastly under the 1e-2 absmax threshold.
__device__ __forceinline__ float sigmoid_f(float x) {
    float e = __expf(-x);
    return __builtin_amdgcn_rcpf(1.0f + e);
}
__device__ __forceinline__ float tanh_f(float x) {
    float e = __expf(2.0f * x);
    return 1.0f - 2.0f * __builtin_amdgcn_rcpf(e + 1.0f);
}

// 2-term f16 dot with f32 accumulate (v_dot2_f32_f16), with safe fallback.
__device__ __forceinline__ float dot2f(half2v a, half2v b, float c) {
#if __has_builtin(__builtin_amdgcn_fdot2)
    return __builtin_amdgcn_fdot2(a, b, c, false);
#else
    return fmaf((float)a.x, (float)b.x, fmaf((float)a.y, (float)b.y, c));
#endif
}

// quad-lane exchanges via DPP quad_perm (1-cycle VALU, no LDS)
__device__ __forceinline__ float dpp_xor1(float v) {   // lanes 0<->1, 2<->3
    return __int_as_float(__builtin_amdgcn_mov_dpp(__float_as_int(v), 0xB1, 0xF, 0xF, true));
}
__device__ __forceinline__ float dpp_xor2(float v) {   // lanes 0<->2, 1<->3
    return __int_as_float(__builtin_amdgcn_mov_dpp(__float_as_int(v), 0x4E, 0xF, 0xF, true));
}

// ---------------------------------------------------------------------------
// Phase 1: projected-token table  P[v][g] = sum_e emb[v][e]*K[e][g] + bias[g]
// (20000 distinct tokens vs 131072 (b,t) pairs -> 3.3x less GEMM work; 41 MB
// L3-resident table instead of 256 MB of zx.)
// ---------------------------------------------------------------------------
__global__ __launch_bounds__(512, 2) void proj_kernel(
    const float* __restrict__ emb, const float* __restrict__ wk,
    const float* __restrict__ bias, float* __restrict__ P) {
    const int col = threadIdx.x;
    const int v0  = blockIdx.x * 16;

    __shared__ float elds[16 * EE];
    ((float4*)elds)[col] = ((const float4*)(emb + (size_t)v0 * EE))[col];
    __syncthreads();

    float bcol = bias[col];
    float acc[16];
#pragma unroll
    for (int r = 0; r < 16; ++r) acc[r] = bcol;

    const float4* elds4 = (const float4*)elds;
    for (int e0 = 0; e0 < EE; e0 += 4) {
        float k0 = wk[(e0 + 0) * G4 + col];
        float k1 = wk[(e0 + 1) * G4 + col];
        float k2 = wk[(e0 + 2) * G4 + col];
        float k3 = wk[(e0 + 3) * G4 + col];
#pragma unroll
        for (int r = 0; r < 16; ++r) {
            float4 ev = elds4[r * 32 + (e0 >> 2)];
            acc[r] = fmaf(ev.x, k0, acc[r]);
            acc[r] = fmaf(ev.y, k1, acc[r]);
            acc[r] = fmaf(ev.z, k2, acc[r]);
            acc[r] = fmaf(ev.w, k3, acc[r]);
        }
    }
#pragma unroll
    for (int r = 0; r < 16; ++r)
        P[(size_t)(v0 + r) * G4 + col] = acc[r];
}

// ---------------------------------------------------------------------------
// Phase 2: sequential LSTM. One block per batch row; 512 threads =
// 128 units x 4 slices. Thread (u,q) holds rk[32q:32q+32, {u,u+128,u+256,
// u+384}] as 64 packed-f16 VGPRs and computes 4 gate partials via
// v_dot2_f32_f16; quad DPP butterfly completes the 128-dim dot. All quad
// lanes then redundantly compute activations + (c,h) update -> no second
// barrier, no gate LDS. h is double-buffered f16 in LDS (1 barrier/step).
// ---------------------------------------------------------------------------
__global__ __launch_bounds__(512, 2) void lstm_kernel(
    const int* __restrict__ tokens, const float* __restrict__ rk,
    const float* __restrict__ P, const float* __restrict__ dense_w,
    const float* __restrict__ dense_b, float* __restrict__ out) {
    const int tid = threadIdx.x;
    const int u   = tid >> 2;   // unit 0..127
    const int q   = tid & 3;    // 32-dim slice 0..3
    const int b   = blockIdx.x;

    __shared__ __align__(16) _Float16 hh[2][UU];  // double-buffered h (f16)
    __shared__ float red[8];

    // ---- pack recurrent weights into 64 VGPRs of v2f16 ----
    // w[g][k] covers h[32q+2k], h[32q+2k+1] for gate column u+128g
    half2v w[4][16];
    const float* rkbase = rk + (size_t)(32 * q) * G4;
#pragma unroll
    for (int g = 0; g < 4; ++g) {
        const int c = u + 128 * g;
#pragma unroll
        for (int k = 0; k < 16; ++k) {
            float a0 = rkbase[(2 * k + 0) * G4 + c];
            float a1 = rkbase[(2 * k + 1) * G4 + c];
            half2v hw;
            hw.x = (_Float16)a0;
            hw.y = (_Float16)a1;
            w[g][k] = hw;
        }
    }

    if (tid < UU) hh[0][tid] = (_Float16)0.f;   // h0 = 0
    float c_state = 0.f, hv = 0.f;

    const int* trow = tokens + (size_t)b * TT;
    float pv[4];
    {
        int tok0 = trow[0];
#pragma unroll
        for (int g = 0; g < 4; ++g) pv[g] = P[(size_t)tok0 * G4 + u + 128 * g];
    }
    __syncthreads();

    for (int t = 0; t < TT; ++t) {
        // --- prefetch next step's P values (hides L3/HBM gather latency) ---
        int tokn = trow[(t + 1 < TT) ? (t + 1) : (TT - 1)];
        float pvn[4];
#pragma unroll
        for (int g = 0; g < 4; ++g) pvn[g] = P[(size_t)tokn * G4 + u + 128 * g];

        // --- read this thread's 32-value h slice (packed f16, 64B) ---
        const half2v* hrow = (const half2v*)&hh[t & 1][32 * q];
        half2v hr[16];
#pragma unroll
        for (int k = 0; k < 16; ++k) hr[k] = hrow[k];

        // --- 4 gate partial dots over the slice (8 independent chains) ---
        float acc0[4], acc1[4];
#pragma unroll
        for (int g = 0; g < 4; ++g) { acc0[g] = 0.f; acc1[g] = 0.f; }
#pragma unroll
        for (int k = 0; k < 8; ++k) {
#pragma unroll
            for (int g = 0; g < 4; ++g) {
                acc0[g] = dot2f(hr[2 * k + 0], w[g][2 * k + 0], acc0[g]);
                acc1[g] = dot2f(hr[2 * k + 1], w[g][2 * k + 1], acc1[g]);
            }
        }

        // --- complete 128-dim dot across the quad (DPP butterfly) ---
        float z[4];
#pragma unroll
        for (int g = 0; g < 4; ++g) {
            float s = acc0[g] + acc1[g];
            s += dpp_xor1(s);
            s += dpp_xor2(s);          // all 4 lanes now hold the full sum
            z[g] = s + pv[g];
        }

        // --- activations + state (redundant x4 within quad, bit-identical) ---
        float gi = sigmoid_f(z[0]);
        float gf = sigmoid_f(z[1]);
        float gg = tanh_f(z[2]);
        float go = sigmoid_f(z[3]);
        c_state = fmaf(gf, c_state, gi * gg);
        hv      = go * tanh_f(c_state);

        if (q == 0) hh[(t + 1) & 1][u] = (_Float16)hv;  // publish h
#pragma unroll
        for (int g = 0; g < 4; ++g) pv[g] = pvn[g];
        __syncthreads();
    }

    // --- dense sigmoid head: out[b] = sigmoid(h @ w + b), parallel reduce ---
    float val = (q == 0) ? hv * dense_w[u] : 0.f;
#pragma unroll
    for (int off = 32; off > 0; off >>= 1) val += __shfl_xor(val, off, 64);
    if ((tid & 63) == 0) red[tid >> 6] = val;
    __syncthreads();
    if (tid == 0) {
        float s = dense_b[0];
#pragma unroll
        for (int wv = 0; wv < 8; ++wv) s += red[wv];
        out[b] = sigmoid_f(s);
    }
}

extern "C" void kernel_launch(void* const* d_in, const int* in_sizes, int n_in,
                              void* d_out, int out_size, void* d_ws, size_t ws_size,
                              hipStream_t stream) {
    const int*   tokens = (const int*)  d_in[0];
    const float* emb    = (const float*)d_in[1];
    const float* wk     = (const float*)d_in[2];
    const float* rk     = (const float*)d_in[3];
    const float* bias   = (const float*)d_in[4];
    const float* dw     = (const float*)d_in[5];
    const float* db     = (const float*)d_in[6];
    float* out = (float*)d_out;
    float* P   = (float*)d_ws;     // 20000*512*4 = 40.96 MB scratch

    proj_kernel<<<VV / 16, 512, 0, stream>>>(emb, wk, bias, P);
    lstm_kernel<<<BB, 512, 0, stream>>>(tokens, rk, P, dw, db, out);
}

// Round 3
// 362.526 us; speedup vs baseline: 1.3772x; 1.0518x over previous
//
#include <hip/hip_runtime.h>
#include <hip/hip_bf16.h>

// Problem constants: B,T,V,E,U = 256,512,20000,128,128
#define BB 256
#define TT 512
#define VV 20000
#define EE 128
#define UU 128
#define G4 512   // 4*U gate width

typedef _Float16 half2v __attribute__((ext_vector_type(2)));

// Fast device math: error ~1e-6, vastly under the 1e-2 absmax threshold.
__device__ __forceinline__ float sigmoid_f(float x) {
    float e = __expf(-x);
    return __builtin_amdgcn_rcpf(1.0f + e);
}
__device__ __forceinline__ float tanh_f(float x) {
    float e = __expf(2.0f * x);
    return 1.0f - 2.0f * __builtin_amdgcn_rcpf(e + 1.0f);
}

// 2-term f16 dot with f32 accumulate (v_dot2_f32_f16), with safe fallback.
__device__ __forceinline__ float dot2f(half2v a, half2v b, float c) {
#if __has_builtin(__builtin_amdgcn_fdot2)
    return __builtin_amdgcn_fdot2(a, b, c, false);
#else
    return fmaf((float)a.x, (float)b.x, fmaf((float)a.y, (float)b.y, c));
#endif
}

// quad-lane exchanges via DPP quad_perm (1-cycle VALU, no LDS)
__device__ __forceinline__ float dpp_xor1(float v) {   // lanes 0<->1, 2<->3
    return __int_as_float(__builtin_amdgcn_mov_dpp(__float_as_int(v), 0xB1, 0xF, 0xF, true));
}
__device__ __forceinline__ float dpp_xor2(float v) {   // lanes 0<->2, 1<->3
    return __int_as_float(__builtin_amdgcn_mov_dpp(__float_as_int(v), 0x4E, 0xF, 0xF, true));
}

// ---------------------------------------------------------------------------
// Phase 1: projected-token table  P[v][g] = sum_e emb[v][e]*K[e][g] + bias[g]
// ---------------------------------------------------------------------------
__global__ __launch_bounds__(512, 2) void proj_kernel(
    const float* __restrict__ emb, const float* __restrict__ wk,
    const float* __restrict__ bias, float* __restrict__ P) {
    const int col = threadIdx.x;
    const int v0  = blockIdx.x * 16;

    __shared__ float elds[16 * EE];
    ((float4*)elds)[col] = ((const float4*)(emb + (size_t)v0 * EE))[col];
    __syncthreads();

    float bcol = bias[col];
    float acc[16];
#pragma unroll
    for (int r = 0; r < 16; ++r) acc[r] = bcol;

    const float4* elds4 = (const float4*)elds;
    for (int e0 = 0; e0 < EE; e0 += 4) {
        float k0 = wk[(e0 + 0) * G4 + col];
        float k1 = wk[(e0 + 1) * G4 + col];
        float k2 = wk[(e0 + 2) * G4 + col];
        float k3 = wk[(e0 + 3) * G4 + col];
#pragma unroll
        for (int r = 0; r < 16; ++r) {
            float4 ev = elds4[r * 32 + (e0 >> 2)];
            acc[r] = fmaf(ev.x, k0, acc[r]);
            acc[r] = fmaf(ev.y, k1, acc[r]);
            acc[r] = fmaf(ev.z, k2, acc[r]);
            acc[r] = fmaf(ev.w, k3, acc[r]);
        }
    }
#pragma unroll
    for (int r = 0; r < 16; ++r)
        P[(size_t)(v0 + r) * G4 + col] = acc[r];
}

// ---------------------------------------------------------------------------
// Phase 2: sequential LSTM. One block per batch row; 512 threads =
// 128 units x 4 slices. Thread (u,q) holds rk[32q:32q+32, {u,u+128g}] as 64
// pinned f16x2 VGPRs (asm pin forbids the compiler from re-loading them in
// the t-loop — that reload was round 2's hidden cost). Quad DPP butterfly
// completes each 128-dim dot; P values enter the butterfly de-duplicated
// (lane q contributes gate q's P). One barrier per step.
// ---------------------------------------------------------------------------
__global__ __launch_bounds__(512, 2) void lstm_kernel(
    const int* __restrict__ tokens, const float* __restrict__ rk,
    const float* __restrict__ P, const float* __restrict__ dense_w,
    const float* __restrict__ dense_b, float* __restrict__ out) {
    const int tid = threadIdx.x;
    const int u   = tid >> 2;   // unit 0..127
    const int q   = tid & 3;    // 32-dim slice 0..3
    const int b   = blockIdx.x;

    __shared__ __align__(16) _Float16 hh[2][UU];  // double-buffered h (f16)
    __shared__ float red[8];

    // ---- pack recurrent weights into 64 pinned VGPRs ----
    // wbits[g*16+m] = f16x2 of rk[32q+2m, u+128g], rk[32q+2m+1, u+128g]
    int wbits[64];
    const float* rkbase = rk + (size_t)(32 * q) * G4;
#pragma unroll
    for (int g = 0; g < 4; ++g) {
        const int c = u + 128 * g;
#pragma unroll
        for (int m = 0; m < 16; ++m) {
            float a0 = rkbase[(2 * m + 0) * G4 + c];
            float a1 = rkbase[(2 * m + 1) * G4 + c];
            half2v hw;
            hw.x = (_Float16)a0;
            hw.y = (_Float16)a1;
            wbits[g * 16 + m] = __builtin_bit_cast(int, hw);
            // Pin: value now defined by asm -> cannot be rematerialized/sunk
            asm volatile("" : "+v"(wbits[g * 16 + m]));
        }
    }
#define WREG(g, m) __builtin_bit_cast(half2v, wbits[(g) * 16 + (m)])

    if (tid < UU) hh[0][tid] = (_Float16)0.f;   // h0 = 0
    float c_state = 0.f, hv = 0.f;

    const int* trow = tokens + (size_t)b * TT;
    // lane q owns gate q's P value (no quad redundancy)
    float pv = P[(size_t)trow[0] * G4 + u + 128 * q];
    __syncthreads();

    for (int t = 0; t < TT; ++t) {
        // --- prefetch next step's P value (hides L3/HBM gather latency) ---
        int tokn  = trow[(t + 1 < TT) ? (t + 1) : (TT - 1)];
        float pvn = P[(size_t)tokn * G4 + u + 128 * q];

        // --- 4 gate partial dots over this 32-dim h slice ---
        // init: inject pv into the quad sum exactly once (lane q -> gate q)
        float acc0[4], acc1[4];
#pragma unroll
        for (int g = 0; g < 4; ++g) {
            acc0[g] = (q == g) ? pv : 0.f;
            acc1[g] = 0.f;
        }
        const int4* hrow = (const int4*)&hh[t & 1][32 * q];  // 64B, 4x b128
#pragma unroll
        for (int k = 0; k < 4; ++k) {
            int4 hv4 = hrow[k];
            half2v h0 = __builtin_bit_cast(half2v, hv4.x);
            half2v h1 = __builtin_bit_cast(half2v, hv4.y);
            half2v h2 = __builtin_bit_cast(half2v, hv4.z);
            half2v h3 = __builtin_bit_cast(half2v, hv4.w);
#pragma unroll
            for (int g = 0; g < 4; ++g) {
                acc0[g] = dot2f(h0, WREG(g, 4 * k + 0), acc0[g]);
                acc1[g] = dot2f(h1, WREG(g, 4 * k + 1), acc1[g]);
                acc0[g] = dot2f(h2, WREG(g, 4 * k + 2), acc0[g]);
                acc1[g] = dot2f(h3, WREG(g, 4 * k + 3), acc1[g]);
            }
        }

        // --- complete 128-dim dot + P across the quad (DPP butterfly) ---
        float z[4];
#pragma unroll
        for (int g = 0; g < 4; ++g) {
            float s = acc0[g] + acc1[g];
            s += dpp_xor1(s);
            s += dpp_xor2(s);          // all 4 lanes hold full z[g]
            z[g] = s;
        }

        // --- activations + state (redundant x4 within quad, bit-identical) ---
        float gi = sigmoid_f(z[0]);
        float gf = sigmoid_f(z[1]);
        float gg = tanh_f(z[2]);
        float go = sigmoid_f(z[3]);
        c_state = fmaf(gf, c_state, gi * gg);
        hv      = go * tanh_f(c_state);

        if (q == 0) hh[(t + 1) & 1][u] = (_Float16)hv;  // publish h
        pv = pvn;
        __syncthreads();
    }

    // --- dense sigmoid head: out[b] = sigmoid(h @ w + b), parallel reduce ---
    float val = (q == 0) ? hv * dense_w[u] : 0.f;
#pragma unroll
    for (int off = 32; off > 0; off >>= 1) val += __shfl_xor(val, off, 64);
    if ((tid & 63) == 0) red[tid >> 6] = val;
    __syncthreads();
    if (tid == 0) {
        float s = dense_b[0];
#pragma unroll
        for (int wv = 0; wv < 8; ++wv) s += red[wv];
        out[b] = sigmoid_f(s);
    }
}

extern "C" void kernel_launch(void* const* d_in, const int* in_sizes, int n_in,
                              void* d_out, int out_size, void* d_ws, size_t ws_size,
                              hipStream_t stream) {
    const int*   tokens = (const int*)  d_in[0];
    const float* emb    = (const float*)d_in[1];
    const float* wk     = (const float*)d_in[2];
    const float* rk     = (const float*)d_in[3];
    const float* bias   = (const float*)d_in[4];
    const float* dw     = (const float*)d_in[5];
    const float* db     = (const float*)d_in[6];
    float* out = (float*)d_out;
    float* P   = (float*)d_ws;     // 20000*512*4 = 40.96 MB scratch

    proj_kernel<<<VV / 16, 512, 0, stream>>>(emb, wk, bias, P);
    lstm_kernel<<<BB, 512, 0, stream>>>(tokens, rk, P, dw, db, out);
}

// Round 4
// 303.091 us; speedup vs baseline: 1.6472x; 1.1961x over previous
//
#include <hip/hip_runtime.h>
#include <hip/hip_bf16.h>

// Problem constants: B,T,V,E,U = 256,512,20000,128,128
#define BB 256
#define TT 512
#define VV 20000
#define EE 128
#define UU 128
#define G4 512   // 4*U gate width

typedef _Float16 f16x8 __attribute__((ext_vector_type(8)));
typedef float    f32x4 __attribute__((ext_vector_type(4)));

// Fast device math: error ~1e-6, vastly under the 1e-2 absmax threshold.
__device__ __forceinline__ float sigmoid_f(float x) {
    float e = __expf(-x);
    return __builtin_amdgcn_rcpf(1.0f + e);
}
__device__ __forceinline__ float tanh_f(float x) {
    float e = __expf(2.0f * x);
    return 1.0f - 2.0f * __builtin_amdgcn_rcpf(e + 1.0f);
}

// ---------------------------------------------------------------------------
// Phase 1: projected-token table  P[v][g] = sum_e emb[v][e]*K[e][g] + bias[g]
// (20000 distinct tokens vs 131072 (b,t) pairs; 41 MB L3-resident table.)
// ---------------------------------------------------------------------------
__global__ __launch_bounds__(512, 2) void proj_kernel(
    const float* __restrict__ emb, const float* __restrict__ wk,
    const float* __restrict__ bias, float* __restrict__ P) {
    const int col = threadIdx.x;
    const int v0  = blockIdx.x * 16;

    __shared__ float elds[16 * EE];
    ((float4*)elds)[col] = ((const float4*)(emb + (size_t)v0 * EE))[col];
    __syncthreads();

    float bcol = bias[col];
    float acc[16];
#pragma unroll
    for (int r = 0; r < 16; ++r) acc[r] = bcol;

    const float4* elds4 = (const float4*)elds;
    for (int e0 = 0; e0 < EE; e0 += 4) {
        float k0 = wk[(e0 + 0) * G4 + col];
        float k1 = wk[(e0 + 1) * G4 + col];
        float k2 = wk[(e0 + 2) * G4 + col];
        float k3 = wk[(e0 + 3) * G4 + col];
#pragma unroll
        for (int r = 0; r < 16; ++r) {
            float4 ev = elds4[r * 32 + (e0 >> 2)];
            acc[r] = fmaf(ev.x, k0, acc[r]);
            acc[r] = fmaf(ev.y, k1, acc[r]);
            acc[r] = fmaf(ev.z, k2, acc[r]);
            acc[r] = fmaf(ev.w, k3, acc[r]);
        }
    }
#pragma unroll
    for (int r = 0; r < 16; ++r)
        P[(size_t)(v0 + r) * G4 + col] = acc[r];
}

// ---------------------------------------------------------------------------
// Phase 2: sequential LSTM via MFMA. One block per batch row, 8 waves.
// Wave w owns gate-columns {i,f,c,o} x units [16w,16w+16): 16 B-fragments
// of v_mfma_f32_16x16x32_f16 (64 VGPRs), loaded ONCE before the t-loop —
// the compiler keeps MFMA fragments register-resident (standard GEMM
// pattern), unlike the scalar arrays of rounds 2-3 which it spilled.
// A-fragment trick: every lane loads the same h k-slice (A[m][k]=h[k] for
// all m), and C-init replicates P across rows -> all 16 D-rows hold the
// same z; activations run on all 64 lanes redundantly (no divergence).
// One barrier per step; h exchanged via a 512 B double-buffered LDS array.
// ---------------------------------------------------------------------------
__global__ __launch_bounds__(512, 2) void lstm_kernel(
    const int* __restrict__ tokens, const float* __restrict__ rk,
    const float* __restrict__ P, const float* __restrict__ dense_w,
    const float* __restrict__ dense_b, float* __restrict__ out) {
    const int tid = threadIdx.x;
    const int w   = tid >> 6;       // wave 0..7
    const int l   = tid & 63;       // lane
    const int j   = l & 15;         // n index within 16-wide tile
    const int kq  = l >> 4;         // k-quarter 0..3
    const int b   = blockIdx.x;
    const int ucol = 16 * w + j;    // this lane's unit (column within gate)

    __shared__ __align__(16) _Float16 hbuf[2][UU];  // double-buffered h
    __shared__ float red[8];

    // ---- B-fragments: bf[kt][g][i] = rk[32kt+8kq+i][g*128 + ucol] (f16) ----
    f16x8 bf[4][4];
#pragma unroll
    for (int kt = 0; kt < 4; ++kt) {
#pragma unroll
        for (int g = 0; g < 4; ++g) {
            f16x8 v;
#pragma unroll
            for (int i = 0; i < 8; ++i) {
                v[i] = (_Float16)rk[(size_t)(32 * kt + 8 * kq + i) * G4
                                    + g * 128 + ucol];
            }
            bf[kt][g] = v;
        }
    }

    if (tid < UU) hbuf[0][tid] = (_Float16)0.f;   // h0 = 0
    float c_state = 0.f, hv = 0.f;

    const int* trow = tokens + (size_t)b * TT;
    float pv[4];
    {
        int tok0 = trow[0];
#pragma unroll
        for (int g = 0; g < 4; ++g)
            pv[g] = P[(size_t)tok0 * G4 + g * 128 + ucol];
    }
    __syncthreads();

    for (int t = 0; t < TT; ++t) {
        // --- prefetch next step's P values (hides L3/HBM gather latency) ---
        int tokn = trow[(t + 1 < TT) ? (t + 1) : (TT - 1)];
        float pvn[4];
#pragma unroll
        for (int g = 0; g < 4; ++g)
            pvn[g] = P[(size_t)tokn * G4 + g * 128 + ucol];

        // --- A-fragments: af[kt][i] = h[32kt + 8kq + i] (same for all m) ---
        f16x8 af[4];
#pragma unroll
        for (int kt = 0; kt < 4; ++kt)
            af[kt] = *(const f16x8*)&hbuf[t & 1][32 * kt + 8 * kq];

        // --- z = P + h @ R : 4 independent acc chains, 16 MFMA ---
        f32x4 acc[4];
#pragma unroll
        for (int g = 0; g < 4; ++g) acc[g] = (f32x4){pv[g], pv[g], pv[g], pv[g]};
#pragma unroll
        for (int kt = 0; kt < 4; ++kt) {
#pragma unroll
            for (int g = 0; g < 4; ++g)
                acc[g] = __builtin_amdgcn_mfma_f32_16x16x32_f16(
                             af[kt], bf[kt][g], acc[g], 0, 0, 0);
        }

        // --- activations + state (all rows identical; use reg 0) ---
        float gi = sigmoid_f(acc[0][0]);
        float gf = sigmoid_f(acc[1][0]);
        float gg = tanh_f(acc[2][0]);
        float go = sigmoid_f(acc[3][0]);
        c_state = fmaf(gf, c_state, gi * gg);
        hv      = go * tanh_f(c_state);

        if (kq == 0) hbuf[(t + 1) & 1][ucol] = (_Float16)hv;  // publish h
#pragma unroll
        for (int g = 0; g < 4; ++g) pv[g] = pvn[g];
        __syncthreads();
    }

    // --- dense sigmoid head: out[b] = sigmoid(h @ w + b) ---
    float val = (kq == 0) ? hv * dense_w[ucol] : 0.f;
#pragma unroll
    for (int off = 32; off > 0; off >>= 1) val += __shfl_xor(val, off, 64);
    if (l == 0) red[w] = val;
    __syncthreads();
    if (tid == 0) {
        float s = dense_b[0];
#pragma unroll
        for (int i = 0; i < 8; ++i) s += red[i];
        out[b] = sigmoid_f(s);
    }
}

extern "C" void kernel_launch(void* const* d_in, const int* in_sizes, int n_in,
                              void* d_out, int out_size, void* d_ws, size_t ws_size,
                              hipStream_t stream) {
    const int*   tokens = (const int*)  d_in[0];
    const float* emb    = (const float*)d_in[1];
    const float* wk     = (const float*)d_in[2];
    const float* rk     = (const float*)d_in[3];
    const float* bias   = (const float*)d_in[4];
    const float* dw     = (const float*)d_in[5];
    const float* db     = (const float*)d_in[6];
    float* out = (float*)d_out;
    float* P   = (float*)d_ws;     // 20000*512*4 = 40.96 MB scratch

    proj_kernel<<<VV / 16, 512, 0, stream>>>(emb, wk, bias, P);
    lstm_kernel<<<BB, 512, 0, stream>>>(tokens, rk, P, dw, db, out);
}